// Round 12
// baseline (227.333 us; speedup 1.0000x reference)
//
#include <hip/hip_runtime.h>
#include <hip/hip_fp16.h>

using i32x4  = __attribute__((ext_vector_type(4)))  int;
using i32x16 = __attribute__((ext_vector_type(16))) int;

static constexpr int M  = 4 * 2048;   // 8192 rows (B*S)
static constexpr int N  = 4096;       // OUT_F
static constexpr int K  = 4096;       // IN_F
static constexpr int BM = 128, BN = 128, BK = 64;
static constexpr int NT = K / BK;     // 64 K-tiles
static constexpr int TILE = BM * BK;  // 8192 bytes per packed int8 tile

// ---------------- fused pack kernel: int32 -> blocked int8 tiles -------------
// tile (8 KB): [kg(4)][row(128)][16B]  wa: [M/128][NT][tile], wb: [N/128][NT][tile]
static constexpr int PX_BLOCKS = (int)((size_t)M * K / 16 / 256);  // 8192
static constexpr int PW_BLOCKS = (int)((size_t)N * K / 16 / 256);  // 4096

__device__ __forceinline__ unsigned pack4(i32x4 v) {
  return (unsigned)((v.x & 255) | ((v.y & 255) << 8) | ((v.z & 255) << 16) | (v.w << 24));
}

__global__ __launch_bounds__(256) void pack_kernel(const int* __restrict__ x,
                                                   const int* __restrict__ w,
                                                   unsigned char* __restrict__ wa,
                                                   unsigned char* __restrict__ wb) {
  if (blockIdx.x < PX_BLOCKS) {
    unsigned g = blockIdx.x * 256 + threadIdx.x;     // dest 16B granule, < M*K/16
    unsigned tile = g >> 9, gt = g & 511;
    unsigned kg = gt >> 7, row = gt & 127;
    unsigned br = tile >> 6, kt = tile & 63;
    const int* src = x + ((size_t)(br * 128 + row) * K + kt * 64 + kg * 16);
    i32x4 v0 = *(const i32x4*)(src + 0);
    i32x4 v1 = *(const i32x4*)(src + 4);
    i32x4 v2 = *(const i32x4*)(src + 8);
    i32x4 v3 = *(const i32x4*)(src + 12);
    i32x4 d;
    d.x = (int)pack4(v0); d.y = (int)pack4(v1); d.z = (int)pack4(v2); d.w = (int)pack4(v3);
    *(i32x4*)(wa + (size_t)g * 16) = d;
  } else {
    unsigned g = (blockIdx.x - PX_BLOCKS) * 256 + threadIdx.x;  // < N*K/16
    unsigned tile = g >> 9, gt = g & 511;
    unsigned kg = gt >> 7, col = gt & 127;
    unsigned bn = tile >> 6, kt = tile & 63;
    unsigned n  = bn * 128 + col;
    unsigned k0 = kt * 64 + kg * 16;
    const int* src = w + (size_t)k0 * N + n;
    i32x4 d;
#pragma unroll
    for (int j = 0; j < 4; ++j) {
      int b0 = src[(size_t)(j * 4 + 0) * N];
      int b1 = src[(size_t)(j * 4 + 1) * N];
      int b2 = src[(size_t)(j * 4 + 2) * N];
      int b3 = src[(size_t)(j * 4 + 3) * N];
      d[j] = (b0 & 255) | ((b1 & 255) << 8) | ((b2 & 255) << 16) | (b3 << 24);
    }
    *(i32x4*)(wb + (size_t)g * 16) = d;
  }
}

// -- GEMM: 128x128, 4 waves (2x2), reg-staged LDS, PREFETCH DISTANCE 2 -------
// set P holds even tiles, set Q odd tiles; GLOAD(t+2) issued at tile t,
// SWRITE(t+1) at tile t's end -> every load has ~2 tiles of compute in flight.

__global__ __launch_bounds__(256) void gemm_i8(const unsigned char* __restrict__ wa,
                                               const unsigned char* __restrict__ wb,
                                               const __half* __restrict__ bias,
                                               const float* __restrict__ alphaP,
                                               float* __restrict__ out) {
  __shared__ __align__(16) unsigned char As[2][TILE];   // 16 KB
  __shared__ __align__(16) unsigned char Bs[2][TILE];   // 16 KB -> 32 KB total

  const int tid  = threadIdx.x;
  const int lane = tid & 63;
  const int w    = tid >> 6;            // wave 0..3
  const int wr   = w >> 1, wc = w & 1;  // 2 x 2 grid; wave tile 64 x 64
  const int l31  = lane & 31;
  const int kgl  = lane >> 5;

  const int bc = blockIdx.x;            // 0..31 (fast: neighbors share A panel)
  const int br = blockIdx.y;            // 0..63

  const unsigned char* ga = wa + (size_t)br * NT * TILE;
  const unsigned char* gb = wb + (size_t)bc * NT * TILE;

  const int arow = wr * 64 + l31;       // A frag row base (per lane)
  const int bcol = wc * 64 + l31;       // B frag col base (per lane)

  // two staging sets (2 x 16B A + 2 x 16B B each), all names static (rule #20)
  i32x4 p0, p1, p2, p3;   // set P (even tiles)
  i32x4 q0, q1, q2, q3;   // set Q (odd tiles)

#define GLOAD_P(T) do {                                              \
    const i32x4* ap = (const i32x4*)(ga + (size_t)(T) * TILE);       \
    const i32x4* bp = (const i32x4*)(gb + (size_t)(T) * TILE);       \
    p0 = ap[tid]; p1 = ap[tid + 256];                                \
    p2 = bp[tid]; p3 = bp[tid + 256];                                \
  } while (0)

#define GLOAD_Q(T) do {                                              \
    const i32x4* ap = (const i32x4*)(ga + (size_t)(T) * TILE);       \
    const i32x4* bp = (const i32x4*)(gb + (size_t)(T) * TILE);       \
    q0 = ap[tid]; q1 = ap[tid + 256];                                \
    q2 = bp[tid]; q3 = bp[tid + 256];                                \
  } while (0)

#define SWRITE_P(BUF) do {                                           \
    i32x4* aw = (i32x4*)&As[BUF][0];                                 \
    i32x4* bw = (i32x4*)&Bs[BUF][0];                                 \
    aw[tid] = p0; aw[tid + 256] = p1;                                \
    bw[tid] = p2; bw[tid + 256] = p3;                                \
  } while (0)

#define SWRITE_Q(BUF) do {                                           \
    i32x4* aw = (i32x4*)&As[BUF][0];                                 \
    i32x4* bw = (i32x4*)&Bs[BUF][0];                                 \
    aw[tid] = q0; aw[tid + 256] = q1;                                \
    bw[tid] = q2; bw[tid + 256] = q3;                                \
  } while (0)

  i32x16 acc[2][2] = {};

#define COMPUTE(BUF) do {                                                      \
    const unsigned char* Ab = &As[BUF][0] + kgl * 2048;                        \
    const unsigned char* Bb = &Bs[BUF][0] + kgl * 2048;                        \
    _Pragma("unroll")                                                          \
    for (int kc = 0; kc < 2; ++kc) {                                           \
      const unsigned char* Ap = Ab + kc * 4096;                                \
      const unsigned char* Bp = Bb + kc * 4096;                                \
      i32x4 a0 = *(const i32x4*)(Ap + (arow +  0) * 16);                       \
      i32x4 a1 = *(const i32x4*)(Ap + (arow + 32) * 16);                       \
      i32x4 b0 = *(const i32x4*)(Bp + (bcol +  0) * 16);                       \
      i32x4 b1 = *(const i32x4*)(Bp + (bcol + 32) * 16);                       \
      acc[0][0] = __builtin_amdgcn_mfma_i32_32x32x32_i8(a0, b0, acc[0][0], 0, 0, 0); \
      acc[0][1] = __builtin_amdgcn_mfma_i32_32x32x32_i8(a0, b1, acc[0][1], 0, 0, 0); \
      acc[1][0] = __builtin_amdgcn_mfma_i32_32x32x32_i8(a1, b0, acc[1][0], 0, 0, 0); \
      acc[1][1] = __builtin_amdgcn_mfma_i32_32x32x32_i8(a1, b1, acc[1][1], 0, 0, 0); \
    }                                                                          \
  } while (0)

  // prologue: tile0 -> LDS buf0; tile1 loads in flight (set Q)
  GLOAD_P(0);
  SWRITE_P(0);        // compiler inserts vmcnt for p* before the ds_writes
  GLOAD_Q(1);
  __syncthreads();

  for (int t = 0; t < NT; t += 2) {
    // even tile t: compute buf0; issue even-tile loads t+2 (set P is free)
    if (t + 2 < NT) GLOAD_P(t + 2);
    COMPUTE(0);
    __builtin_amdgcn_sched_barrier(0);   // keep vmcnt-wait + ds_write below MFMAs
    if (t + 1 < NT) SWRITE_Q(1);         // tile t+1: issued at t-1 (2 tiles in flight)
    __syncthreads();

    // odd tile t+1: compute buf1; issue odd-tile loads t+3 (set Q is free)
    if (t + 3 < NT) GLOAD_Q(t + 3);
    COMPUTE(1);
    __builtin_amdgcn_sched_barrier(0);
    if (t + 2 < NT) SWRITE_P(0);         // tile t+2: issued at t (2 tiles in flight)
    __syncthreads();
  }

  // epilogue: C/D layout col=lane&31, row=(r&3)+8*(r>>2)+4*(lane>>5)
  const float alpha = *alphaP;
  const int row0 = br * 128 + wr * 64 + 4 * kgl;
  const int col0 = bc * 128 + wc * 64 + l31;
#pragma unroll
  for (int ni = 0; ni < 2; ++ni) {
    const int col = col0 + ni * 32;
    const float bf = __half2float(bias[col]);
#pragma unroll
    for (int mi = 0; mi < 2; ++mi) {
#pragma unroll
      for (int r = 0; r < 16; ++r) {
        const int row = row0 + mi * 32 + (r & 3) + 8 * (r >> 2);
        out[(size_t)row * N + col] = ((float)acc[mi][ni][r] + bf) * alpha;
      }
    }
  }
#undef COMPUTE
#undef GLOAD_P
#undef GLOAD_Q
#undef SWRITE_P
#undef SWRITE_Q
}

extern "C" void kernel_launch(void* const* d_in, const int* in_sizes, int n_in,
                              void* d_out, int out_size, void* d_ws, size_t ws_size,
                              hipStream_t stream) {
  const int*    x     = (const int*)d_in[0];
  const int*    wgt   = (const int*)d_in[1];
  const __half* bias  = (const __half*)d_in[2];
  const float*  alpha = (const float*)d_in[3];
  float*        out   = (float*)d_out;

  // workspace: packed A (32 MB) + packed B (16 MB) = 48 MB
  unsigned char* wa = (unsigned char*)d_ws;
  unsigned char* wb = wa + (size_t)M * K;

  pack_kernel<<<PX_BLOCKS + PW_BLOCKS, 256, 0, stream>>>(x, wgt, wa, wb);

  dim3 grid(N / BN, M / BM);   // 32 x 64 = 2048 blocks
  gemm_i8<<<grid, 256, 0, stream>>>(wa, wb, bias, alpha, out);
}

// Round 13
// 224.796 us; speedup vs baseline: 1.0113x; 1.0113x over previous
//
#include <hip/hip_runtime.h>
#include <hip/hip_fp16.h>

using i32x4  = __attribute__((ext_vector_type(4)))  int;
using i32x16 = __attribute__((ext_vector_type(16))) int;

static constexpr int M  = 4 * 2048;   // 8192 rows (B*S)
static constexpr int N  = 4096;       // OUT_F
static constexpr int K  = 4096;       // IN_F
static constexpr int BM = 128, BN = 128, BK = 64;
static constexpr int NT = K / BK;     // 64 K-tiles
static constexpr int TILE = BM * BK;  // 8192 bytes per packed int8 tile

// ---------------- fused pack kernel: int32 -> blocked int8 tiles -------------
// tile (8 KB): [kg(4)][row(128)][16B]  wa: [M/128][NT][tile], wb: [N/128][NT][tile]
static constexpr int PX_BLOCKS = (int)((size_t)M * K / 16 / 256);  // 8192
static constexpr int PW_BLOCKS = (int)((size_t)N * K / 16 / 256);  // 4096

__device__ __forceinline__ unsigned pack4(i32x4 v) {
  return (unsigned)((v.x & 255) | ((v.y & 255) << 8) | ((v.z & 255) << 16) | (v.w << 24));
}

__global__ __launch_bounds__(256) void pack_kernel(const int* __restrict__ x,
                                                   const int* __restrict__ w,
                                                   unsigned char* __restrict__ wa,
                                                   unsigned char* __restrict__ wb) {
  if (blockIdx.x < PX_BLOCKS) {
    unsigned g = blockIdx.x * 256 + threadIdx.x;     // dest 16B granule, < M*K/16
    unsigned tile = g >> 9, gt = g & 511;
    unsigned kg = gt >> 7, row = gt & 127;
    unsigned br = tile >> 6, kt = tile & 63;
    const int* src = x + ((size_t)(br * 128 + row) * K + kt * 64 + kg * 16);
    i32x4 v0 = *(const i32x4*)(src + 0);
    i32x4 v1 = *(const i32x4*)(src + 4);
    i32x4 v2 = *(const i32x4*)(src + 8);
    i32x4 v3 = *(const i32x4*)(src + 12);
    i32x4 d;
    d.x = (int)pack4(v0); d.y = (int)pack4(v1); d.z = (int)pack4(v2); d.w = (int)pack4(v3);
    *(i32x4*)(wa + (size_t)g * 16) = d;
  } else {
    unsigned g = (blockIdx.x - PX_BLOCKS) * 256 + threadIdx.x;  // < N*K/16
    unsigned tile = g >> 9, gt = g & 511;
    unsigned kg = gt >> 7, col = gt & 127;
    unsigned bn = tile >> 6, kt = tile & 63;
    unsigned n  = bn * 128 + col;
    unsigned k0 = kt * 64 + kg * 16;
    const int* src = w + (size_t)k0 * N + n;
    i32x4 d;
#pragma unroll
    for (int j = 0; j < 4; ++j) {
      int b0 = src[(size_t)(j * 4 + 0) * N];
      int b1 = src[(size_t)(j * 4 + 1) * N];
      int b2 = src[(size_t)(j * 4 + 2) * N];
      int b3 = src[(size_t)(j * 4 + 3) * N];
      d[j] = (b0 & 255) | ((b1 & 255) << 8) | ((b2 & 255) << 16) | (b3 << 24);
    }
    *(i32x4*)(wb + (size_t)g * 16) = d;
  }
}

// -- GEMM: 128x128, 4 waves (2x2), A reg-staged LDS @ distance 2, B direct ----
// LDS 16 KB (A dbuf only) + ~150 unified regs -> ~3 blocks/CU resident.

__global__ __launch_bounds__(256) void gemm_i8(const unsigned char* __restrict__ wa,
                                               const unsigned char* __restrict__ wb,
                                               const __half* __restrict__ bias,
                                               const float* __restrict__ alphaP,
                                               float* __restrict__ out) {
  __shared__ __align__(16) unsigned char As[2][TILE];   // 16 KB total (A only)

  const int tid  = threadIdx.x;
  const int lane = tid & 63;
  const int w    = tid >> 6;            // wave 0..3
  const int wr   = w >> 1, wc = w & 1;  // 2 x 2 grid; wave tile 64 x 64
  const int l31  = lane & 31;
  const int kgl  = lane >> 5;

  const int bc = blockIdx.x;            // 0..31 (fast: neighbors share A panel)
  const int br = blockIdx.y;            // 0..63

  const unsigned char* ga = wa + (size_t)br * NT * TILE;
  const unsigned char* gb = wb + (size_t)bc * NT * TILE;

  const int arow = wr * 64 + l31;       // A frag row base (per lane)
  const int bcol = wc * 64 + l31;       // B frag col base (per lane)

  // A staging sets (distance 2): P = even tiles, Q = odd tiles
  i32x4 p0, p1, q0, q1;
  // B direct regs (distance 1): [parity][kc][ni], all indices constant
  i32x4 b[2][2][2];

#define GLOADA_P(T) do {                                             \
    const i32x4* ap = (const i32x4*)(ga + (size_t)(T) * TILE);       \
    p0 = ap[tid]; p1 = ap[tid + 256];                                \
  } while (0)

#define GLOADA_Q(T) do {                                             \
    const i32x4* ap = (const i32x4*)(ga + (size_t)(T) * TILE);       \
    q0 = ap[tid]; q1 = ap[tid + 256];                                \
  } while (0)

#define SWRITE_P(BUF) do {                                           \
    i32x4* aw = (i32x4*)&As[BUF][0];                                 \
    aw[tid] = p0; aw[tid + 256] = p1;                                \
  } while (0)

#define SWRITE_Q(BUF) do {                                           \
    i32x4* aw = (i32x4*)&As[BUF][0];                                 \
    aw[tid] = q0; aw[tid + 256] = q1;                                \
  } while (0)

#define BLOAD(PAR, T) do {                                           \
    const unsigned char* bt = gb + (size_t)(T) * TILE;               \
    b[PAR][0][0] = *(const i32x4*)(bt + (kgl    ) * 2048 + (bcol +  0) * 16); \
    b[PAR][0][1] = *(const i32x4*)(bt + (kgl    ) * 2048 + (bcol + 32) * 16); \
    b[PAR][1][0] = *(const i32x4*)(bt + (kgl + 2) * 2048 + (bcol +  0) * 16); \
    b[PAR][1][1] = *(const i32x4*)(bt + (kgl + 2) * 2048 + (bcol + 32) * 16); \
  } while (0)

  i32x16 acc[2][2] = {};

#define COMPUTE(BUF, PAR) do {                                                 \
    const unsigned char* Ab = &As[BUF][0] + kgl * 2048;                        \
    _Pragma("unroll")                                                          \
    for (int kc = 0; kc < 2; ++kc) {                                           \
      const unsigned char* Ap = Ab + kc * 4096;                                \
      i32x4 a0 = *(const i32x4*)(Ap + (arow +  0) * 16);                       \
      i32x4 a1 = *(const i32x4*)(Ap + (arow + 32) * 16);                       \
      acc[0][0] = __builtin_amdgcn_mfma_i32_32x32x32_i8(a0, b[PAR][kc][0], acc[0][0], 0, 0, 0); \
      acc[0][1] = __builtin_amdgcn_mfma_i32_32x32x32_i8(a0, b[PAR][kc][1], acc[0][1], 0, 0, 0); \
      acc[1][0] = __builtin_amdgcn_mfma_i32_32x32x32_i8(a1, b[PAR][kc][0], acc[1][0], 0, 0, 0); \
      acc[1][1] = __builtin_amdgcn_mfma_i32_32x32x32_i8(a1, b[PAR][kc][1], acc[1][1], 0, 0, 0); \
    }                                                                          \
  } while (0)

  // prologue: A(0)->LDS buf0; A(1) in flight (Q); B(0) resident, B(1) in flight
  GLOADA_P(0);
  BLOAD(0, 0);
  SWRITE_P(0);        // compiler inserts vmcnt for p* before the ds_writes
  GLOADA_Q(1);
  BLOAD(1, 1);
  __syncthreads();

  for (int t = 0; t < NT; t += 2) {
    // even tile t: compute buf0 with B par0; issue A(t+2) [P free], B(t+2)->par0 after use
    if (t + 2 < NT) GLOADA_P(t + 2);
    COMPUTE(0, 0);
    if (t + 2 < NT) BLOAD(0, t + 2);     // par0 regs free after COMPUTE above
    __builtin_amdgcn_sched_barrier(0);   // keep vmcnt-wait + ds_write below MFMAs
    if (t + 1 < NT) SWRITE_Q(1);         // A(t+1): issued at t-1 (2 tiles in flight)
    __syncthreads();

    // odd tile t+1: compute buf1 with B par1; issue A(t+3) [Q free], B(t+3)->par1
    if (t + 3 < NT) GLOADA_Q(t + 3);
    COMPUTE(1, 1);
    if (t + 3 < NT) BLOAD(1, t + 3);
    __builtin_amdgcn_sched_barrier(0);
    if (t + 2 < NT) SWRITE_P(0);         // A(t+2): issued at t (2 tiles in flight)
    __syncthreads();
  }

  // epilogue: C/D layout col=lane&31, row=(r&3)+8*(r>>2)+4*(lane>>5)
  const float alpha = *alphaP;
  const int row0 = br * 128 + wr * 64 + 4 * kgl;
  const int col0 = bc * 128 + wc * 64 + l31;
#pragma unroll
  for (int ni = 0; ni < 2; ++ni) {
    const int col = col0 + ni * 32;
    const float bf = __half2float(bias[col]);
#pragma unroll
    for (int mi = 0; mi < 2; ++mi) {
#pragma unroll
      for (int r = 0; r < 16; ++r) {
        const int row = row0 + mi * 32 + (r & 3) + 8 * (r >> 2);
        out[(size_t)row * N + col] = ((float)acc[mi][ni][r] + bf) * alpha;
      }
    }
  }
#undef COMPUTE
#undef GLOADA_P
#undef GLOADA_Q
#undef SWRITE_P
#undef SWRITE_Q
#undef BLOAD
}

extern "C" void kernel_launch(void* const* d_in, const int* in_sizes, int n_in,
                              void* d_out, int out_size, void* d_ws, size_t ws_size,
                              hipStream_t stream) {
  const int*    x     = (const int*)d_in[0];
  const int*    wgt   = (const int*)d_in[1];
  const __half* bias  = (const __half*)d_in[2];
  const float*  alpha = (const float*)d_in[3];
  float*        out   = (float*)d_out;

  // workspace: packed A (32 MB) + packed B (16 MB) = 48 MB
  unsigned char* wa = (unsigned char*)d_ws;
  unsigned char* wb = wa + (size_t)M * K;

  pack_kernel<<<PX_BLOCKS + PW_BLOCKS, 256, 0, stream>>>(x, wgt, wa, wb);

  dim3 grid(N / BN, M / BM);   // 32 x 64 = 2048 blocks
  gemm_i8<<<grid, 256, 0, stream>>>(wa, wb, bias, alpha, out);
}